// Round 1
// 2598.102 us; speedup vs baseline: 1.0504x; 1.0504x over previous
//
#include <hip/hip_runtime.h>

#define B_    16384
#define NPTS  4096
#define LAT   64
#define KCB   1024

// ---------------------------------------------------------------------------
// Big-tile fp32 GEMM: C = act(A[M,K] @ W[K,N] + bias[N])
// BM=BN=128, BK=16, 256 threads, 8x8 micro-tile per thread split 2x(4)+2x(4)
// so LDS fragment reads are broadcast (A) / 2-way free (B).
// Per-output accumulation is sequential in k -> bitwise identical to the
// previous 64-tile kernel (same FMA chain, same bias add, same relu).
// Optional fused squared-error reduction vs X (for dec3 recon loss).
// ---------------------------------------------------------------------------
template<bool RELU, bool FUSE_LOSS>
__global__ __launch_bounds__(256)
void gemm128_kernel(const float* __restrict__ A, const float* __restrict__ W,
                    const float* __restrict__ bias, float* __restrict__ C,
                    int M, int N, int Kd,
                    const float* __restrict__ X, float* __restrict__ loss_acc)
{
    constexpr int BM = 128, BN = 128, BK = 16;
    __shared__ __align__(16) float As[BK][BM + 4];   // stride 132: 16B-aligned rows
    __shared__ __align__(16) float Bs[BK][BN + 4];

    const int tid = threadIdx.x;
    const int tx = tid & 15;          // 0..15 -> cols tx*4 and 64+tx*4
    const int ty = tid >> 4;          // 0..15 -> rows ty*4 and 64+ty*4
    const int m0 = blockIdx.y * BM;
    const int n0 = blockIdx.x * BN;

    float acc[2][2][4][4] = {};       // [rowhalf][colhalf][i][j]

    for (int k0 = 0; k0 < Kd; k0 += BK) {
        // A tile: 128 rows x 16 k, transpose into As[k][m] (512 float4 loads)
        #pragma unroll
        for (int h = 0; h < 2; ++h) {
            const int f  = tid + h * 256;   // 0..511
            const int r  = f >> 2;          // 0..127
            const int c4 = f & 3;           // 0..3
            const float4 a4 = *(const float4*)(A + (size_t)(m0 + r) * Kd + k0 + c4 * 4);
            As[c4 * 4 + 0][r] = a4.x;
            As[c4 * 4 + 1][r] = a4.y;
            As[c4 * 4 + 2][r] = a4.z;
            As[c4 * 4 + 3][r] = a4.w;
        }
        // W tile: 16 k x 128 cols, contiguous float4 stores
        #pragma unroll
        for (int h = 0; h < 2; ++h) {
            const int f = tid + h * 256;
            const int r = f >> 5;           // 0..15
            const int c = f & 31;           // 0..31
            const float4 b4 = *(const float4*)(W + (size_t)(k0 + r) * N + n0 + c * 4);
            *(float4*)&Bs[r][c * 4] = b4;
        }
        __syncthreads();

        #pragma unroll
        for (int kk = 0; kk < BK; ++kk) {
            float a[2][4], b[2][4];
            #pragma unroll
            for (int rh = 0; rh < 2; ++rh) {
                const float4 v = *(const float4*)&As[kk][rh * 64 + ty * 4];
                a[rh][0] = v.x; a[rh][1] = v.y; a[rh][2] = v.z; a[rh][3] = v.w;
            }
            #pragma unroll
            for (int ch = 0; ch < 2; ++ch) {
                const float4 v = *(const float4*)&Bs[kk][ch * 64 + tx * 4];
                b[ch][0] = v.x; b[ch][1] = v.y; b[ch][2] = v.z; b[ch][3] = v.w;
            }
            #pragma unroll
            for (int rh = 0; rh < 2; ++rh)
                #pragma unroll
                for (int i = 0; i < 4; ++i)
                    #pragma unroll
                    for (int ch = 0; ch < 2; ++ch)
                        #pragma unroll
                        for (int j = 0; j < 4; ++j)
                            acc[rh][ch][i][j] += a[rh][i] * b[ch][j];
        }
        __syncthreads();
    }

    // epilogue: bias + relu + store (float4), optional fused loss
    float4 bv[2];
    #pragma unroll
    for (int ch = 0; ch < 2; ++ch)
        bv[ch] = *(const float4*)(bias + n0 + ch * 64 + tx * 4);

    float lsum = 0.f;
    #pragma unroll
    for (int rh = 0; rh < 2; ++rh) {
        #pragma unroll
        for (int i = 0; i < 4; ++i) {
            const int m = m0 + rh * 64 + ty * 4 + i;
            float* crow = C + (size_t)m * N;
            #pragma unroll
            for (int ch = 0; ch < 2; ++ch) {
                const int n = n0 + ch * 64 + tx * 4;
                float4 o;
                o.x = acc[rh][ch][i][0] + bv[ch].x;
                o.y = acc[rh][ch][i][1] + bv[ch].y;
                o.z = acc[rh][ch][i][2] + bv[ch].z;
                o.w = acc[rh][ch][i][3] + bv[ch].w;
                if (RELU) {
                    o.x = fmaxf(o.x, 0.f); o.y = fmaxf(o.y, 0.f);
                    o.z = fmaxf(o.z, 0.f); o.w = fmaxf(o.w, 0.f);
                }
                if (FUSE_LOSS) {
                    const float4 xv = *(const float4*)(X + (size_t)m * N + n);
                    const float d0 = o.x - xv.x, d1 = o.y - xv.y;
                    const float d2 = o.z - xv.z, d3 = o.w - xv.w;
                    lsum += d0 * d0 + d1 * d1 + d2 * d2 + d3 * d3;
                }
                *(float4*)(crow + n) = o;
            }
        }
    }

    if (FUSE_LOSS) {
        __shared__ float red[256];
        red[tid] = lsum;
        __syncthreads();
        for (int s = 128; s > 0; s >>= 1) {
            if (tid < s) red[tid] += red[tid + s];
            __syncthreads();
        }
        if (tid == 0) atomicAdd(loss_acc, red[0]);
    }
}

// ---------------------------------------------------------------------------
// Small-shape fp32 tiled GEMM (kept for N=64 / K=64 layers): BM=BN=64, BK=16.
// ---------------------------------------------------------------------------
template<bool RELU, bool FUSE_LOSS>
__global__ __launch_bounds__(256)
void gemm_kernel(const float* __restrict__ A, const float* __restrict__ W,
                 const float* __restrict__ bias, float* __restrict__ C,
                 int M, int N, int Kd,
                 const float* __restrict__ X, float* __restrict__ loss_acc)
{
    const int BM = 64, BN = 64, BK = 16;
    __shared__ float As[BK][BM + 4];
    __shared__ float Bs[BK][BN + 4];

    const int tid = threadIdx.x;
    const int tx = tid & 15;
    const int ty = tid >> 4;
    const int m0 = blockIdx.y * BM;
    const int n0 = blockIdx.x * BN;

    float acc[4][4] = {};

    for (int k0 = 0; k0 < Kd; k0 += BK) {
        {
            const int r  = tid >> 2;
            const int c4 = tid & 3;
            const float4 a4 = *(const float4*)(A + (size_t)(m0 + r) * Kd + k0 + c4 * 4);
            As[c4 * 4 + 0][r] = a4.x;
            As[c4 * 4 + 1][r] = a4.y;
            As[c4 * 4 + 2][r] = a4.z;
            As[c4 * 4 + 3][r] = a4.w;
        }
        {
            const int r  = tid >> 4;
            const int c4 = tid & 15;
            const float4 b4 = *(const float4*)(W + (size_t)(k0 + r) * N + n0 + c4 * 4);
            *(float4*)&Bs[r][c4 * 4] = b4;
        }
        __syncthreads();

        #pragma unroll
        for (int kk = 0; kk < BK; ++kk) {
            const float4 a4 = *(const float4*)&As[kk][ty * 4];
            const float4 b4 = *(const float4*)&Bs[kk][tx * 4];
            const float av[4] = {a4.x, a4.y, a4.z, a4.w};
            const float bv[4] = {b4.x, b4.y, b4.z, b4.w};
            #pragma unroll
            for (int i = 0; i < 4; ++i)
                #pragma unroll
                for (int j = 0; j < 4; ++j)
                    acc[i][j] += av[i] * bv[j];
        }
        __syncthreads();
    }

    float lsum = 0.f;
    #pragma unroll
    for (int i = 0; i < 4; ++i) {
        const int m = m0 + ty * 4 + i;
        #pragma unroll
        for (int j = 0; j < 4; ++j) {
            const int n = n0 + tx * 4 + j;
            float v = acc[i][j] + bias[n];
            if (RELU) v = fmaxf(v, 0.f);
            C[(size_t)m * N + n] = v;
            if (FUSE_LOSS) {
                const float d = v - X[(size_t)m * N + n];
                lsum += d * d;
            }
        }
    }

    if (FUSE_LOSS) {
        __shared__ float red[256];
        red[tid] = lsum;
        __syncthreads();
        for (int s = 128; s > 0; s >>= 1) {
            if (tid < s) red[tid] += red[tid + s];
            __syncthreads();
        }
        if (tid == 0) atomicAdd(loss_acc, red[0]);
    }
}

// ---------------------------------------------------------------------------
// Codebook squared norms: sc[c] = |codebook[c]|^2
// ---------------------------------------------------------------------------
__global__ __launch_bounds__(256)
void cbnorm_kernel(const float* __restrict__ cb, float* __restrict__ sc)
{
    const int c = blockIdx.x * blockDim.x + threadIdx.x;
    if (c < KCB) {
        double s = 0.0;
        #pragma unroll 16
        for (int j = 0; j < LAT; ++j) {
            const float v = cb[(size_t)c * LAT + j];
            s += (double)v * (double)v;
        }
        sc[c] = (float)s;
    }
}

// ---------------------------------------------------------------------------
// VQ assignment, 4 rows per block (codebook L2 traffic /4).
// Per-row arithmetic is IDENTICAL to the 1-row version: same thread partition
// of c (tid, tid+256, ...), same double-precision dot order, same tie-break,
// same tree reduction -> bit-identical idx/zq.
// ---------------------------------------------------------------------------
#define VQROWS 4
__global__ __launch_bounds__(256)
void vq_assign_kernel(const float* __restrict__ z, const float* __restrict__ cb,
                      const float* __restrict__ sc, float* __restrict__ zq,
                      float* __restrict__ idx_out)
{
    __shared__ float zrow[VQROWS][LAT];
    __shared__ float sS[VQROWS];
    __shared__ float rd[256];
    __shared__ int   ri[256];

    const int row0 = blockIdx.x * VQROWS;
    const int tid = threadIdx.x;

    // 256 threads load 4*64 = 256 floats
    zrow[tid >> 6][tid & 63] = z[(size_t)row0 * LAT + tid];
    __syncthreads();
    if (tid < VQROWS) {
        double s = 0.0;
        for (int j = 0; j < LAT; ++j) s += (double)zrow[tid][j] * (double)zrow[tid][j];
        sS[tid] = (float)s;
    }
    __syncthreads();

    float bestd[VQROWS];
    int   besti[VQROWS];
    #pragma unroll
    for (int r = 0; r < VQROWS; ++r) { bestd[r] = 1e30f; besti[r] = KCB; }

    for (int c = tid; c < KCB; c += 256) {
        const float4* cb4 = (const float4*)(cb + (size_t)c * LAT);
        double dot[VQROWS] = {};
        #pragma unroll
        for (int q = 0; q < LAT / 4; ++q) {
            const float4 cv = cb4[q];
            #pragma unroll
            for (int r = 0; r < VQROWS; ++r) {
                const float4 zv = ((const float4*)zrow[r])[q];
                dot[r] += (double)zv.x * cv.x + (double)zv.y * cv.y
                        + (double)zv.z * cv.z + (double)zv.w * cv.w;
            }
        }
        #pragma unroll
        for (int r = 0; r < VQROWS; ++r) {
            const float zc = (float)dot[r];
            const float d  = (sS[r] - 2.0f * zc) + sc[c];
            if (d < bestd[r] || (d == bestd[r] && c < besti[r])) {
                bestd[r] = d; besti[r] = c;
            }
        }
    }

    for (int r = 0; r < VQROWS; ++r) {
        rd[tid] = bestd[r]; ri[tid] = besti[r];
        __syncthreads();
        for (int s = 128; s > 0; s >>= 1) {
            if (tid < s) {
                const float od = rd[tid + s];
                const int   oi = ri[tid + s];
                if (od < rd[tid] || (od == rd[tid] && oi < ri[tid])) {
                    rd[tid] = od; ri[tid] = oi;
                }
            }
            __syncthreads();
        }
        const int best = ri[0];
        if (tid == 0) idx_out[row0 + r] = (float)best;
        if (tid < LAT) zq[(size_t)(row0 + r) * LAT + tid] = cb[(size_t)best * LAT + tid];
        __syncthreads();   // rd/ri reused next r
    }
}

// ---------------------------------------------------------------------------
// vq partial: sum over (zq - z)^2 -> atomicAdd into acc
// ---------------------------------------------------------------------------
__global__ __launch_bounds__(256)
void vq_loss_kernel(const float* __restrict__ z, const float* __restrict__ zq,
                    float* __restrict__ acc, int n)
{
    float s = 0.f;
    for (int i = blockIdx.x * blockDim.x + threadIdx.x; i < n;
         i += gridDim.x * blockDim.x) {
        const float d = zq[i] - z[i];
        s += d * d;
    }
    __shared__ float red[256];
    red[threadIdx.x] = s;
    __syncthreads();
    for (int t = 128; t > 0; t >>= 1) {
        if (threadIdx.x < t) red[threadIdx.x] += red[threadIdx.x + t];
        __syncthreads();
    }
    if (threadIdx.x == 0) atomicAdd(acc, red[0]);
}

// ---------------------------------------------------------------------------
// finalize: write [total, recon, vq] scalars
// ---------------------------------------------------------------------------
__global__ void finalize_kernel(const float* __restrict__ acc, float* __restrict__ out3)
{
    const float recon = acc[0] / ((float)B_ * (float)NPTS);
    const float vq    = 1.25f * (acc[1] / ((float)B_ * (float)LAT));
    out3[0] = recon + vq;
    out3[1] = recon;
    out3[2] = vq;
}

// ---------------------------------------------------------------------------
extern "C" void kernel_launch(void* const* d_in, const int* in_sizes, int n_in,
                              void* d_out, int out_size, void* d_ws, size_t ws_size,
                              hipStream_t stream)
{
    const float* x   = (const float*)d_in[0];
    const float* ew1 = (const float*)d_in[1];
    const float* eb1 = (const float*)d_in[2];
    const float* ew2 = (const float*)d_in[3];
    const float* eb2 = (const float*)d_in[4];
    const float* ew3 = (const float*)d_in[5];
    const float* eb3 = (const float*)d_in[6];
    const float* cb  = (const float*)d_in[7];
    const float* dw1 = (const float*)d_in[8];
    const float* db1 = (const float*)d_in[9];
    const float* dw2 = (const float*)d_in[10];
    const float* db2 = (const float*)d_in[11];
    const float* dw3 = (const float*)d_in[12];
    const float* db3 = (const float*)d_in[13];

    float* out_xh     = (float*)d_out;                  // [B, NPTS]
    float* out_idx    = out_xh + (size_t)B_ * NPTS;     // [B] as float
    float* out_losses = out_idx + B_;                   // [3]

    float* ws   = (float*)d_ws;
    float* bufA = ws;                                   // h1 [B,512], reused as h4
    float* bufB = bufA + (size_t)B_ * 512;              // h2 [B,256], reused as h3
    float* z    = bufB + (size_t)B_ * 256;              // [B,64]
    float* zq   = z + (size_t)B_ * LAT;                 // [B,64]
    float* sc   = zq + (size_t)B_ * LAT;                // [KCB]
    float* acc  = sc + KCB;                             // [2]: recon_sum, vq_sum

    hipMemsetAsync(acc, 0, 2 * sizeof(float), stream);

    const dim3 blk(256);

    // encoder
    gemm128_kernel<true,  false><<<dim3(512 / 128, B_ / 128), blk, 0, stream>>>(
        x, ew1, eb1, bufA, B_, 512, NPTS, nullptr, nullptr);
    gemm128_kernel<true,  false><<<dim3(256 / 128, B_ / 128), blk, 0, stream>>>(
        bufA, ew2, eb2, bufB, B_, 256, 512, nullptr, nullptr);
    gemm_kernel<false, false><<<dim3(64 / 64,  B_ / 64), blk, 0, stream>>>(
        bufB, ew3, eb3, z, B_, 64, 256, nullptr, nullptr);

    // vector quantization
    cbnorm_kernel<<<dim3(KCB / 256), blk, 0, stream>>>(cb, sc);
    vq_assign_kernel<<<dim3(B_ / VQROWS), blk, 0, stream>>>(z, cb, sc, zq, out_idx);
    vq_loss_kernel<<<dim3(256), blk, 0, stream>>>(z, zq, acc + 1, B_ * LAT);

    // decoder
    gemm_kernel<true,  false><<<dim3(256 / 64, B_ / 64), blk, 0, stream>>>(
        zq, dw1, db1, bufB, B_, 256, LAT, nullptr, nullptr);
    gemm128_kernel<true,  false><<<dim3(512 / 128, B_ / 128), blk, 0, stream>>>(
        bufB, dw2, db2, bufA, B_, 512, 256, nullptr, nullptr);
    gemm128_kernel<false, true ><<<dim3(NPTS / 128, B_ / 128), blk, 0, stream>>>(
        bufA, dw3, db3, out_xh, B_, NPTS, 512, x, acc + 0);

    finalize_kernel<<<1, 1, 0, stream>>>(acc, out_losses);
}

// Round 2
// 2177.298 us; speedup vs baseline: 1.2535x; 1.1933x over previous
//
#include <hip/hip_runtime.h>

#define B_    16384
#define NPTS  4096
#define LAT   64
#define KCB   1024

typedef __attribute__((ext_vector_type(8))) short bf16x8;
typedef __attribute__((ext_vector_type(4))) float f32x4;

__device__ inline unsigned short f2bf(float x) {
    union { float f; unsigned u; } v; v.f = x;
    unsigned r = v.u + 0x7fffu + ((v.u >> 16) & 1u);   // round-to-nearest-even
    return (unsigned short)(r >> 16);
}
__device__ inline float bf2f(unsigned short h) {
    union { unsigned u; float f; } v; v.u = ((unsigned)h) << 16;
    return v.f;
}

// ---------------------------------------------------------------------------
// Big-tile fp32 GEMM (enc1): BM=BN=128, BK=32, 256 threads, 8x8 micro-tile.
// k ascends exactly as before -> bitwise-identical outputs (idx safety).
// ---------------------------------------------------------------------------
template<bool RELU>
__global__ __launch_bounds__(256)
void gemm128_kernel(const float* __restrict__ A, const float* __restrict__ W,
                    const float* __restrict__ bias, float* __restrict__ C,
                    int M, int N, int Kd)
{
    constexpr int BM = 128, BN = 128, BK = 32;
    __shared__ __align__(16) float As[BK][BM + 4];
    __shared__ __align__(16) float Bs[BK][BN + 4];

    const int tid = threadIdx.x;
    const int tx = tid & 15;
    const int ty = tid >> 4;
    const int m0 = blockIdx.y * BM;
    const int n0 = blockIdx.x * BN;

    float acc[2][2][4][4] = {};

    for (int k0 = 0; k0 < Kd; k0 += BK) {
        // A tile: 128 rows x 32 k -> transpose into As[k][m]  (1024 float4)
        #pragma unroll
        for (int h = 0; h < 4; ++h) {
            const int f  = tid + h * 256;
            const int r  = f >> 3;          // 0..127
            const int c4 = f & 7;           // 0..7
            const float4 a4 = *(const float4*)(A + (size_t)(m0 + r) * Kd + k0 + c4 * 4);
            As[c4 * 4 + 0][r] = a4.x;
            As[c4 * 4 + 1][r] = a4.y;
            As[c4 * 4 + 2][r] = a4.z;
            As[c4 * 4 + 3][r] = a4.w;
        }
        // W tile: 32 k x 128 cols (1024 float4, contiguous)
        #pragma unroll
        for (int h = 0; h < 4; ++h) {
            const int f = tid + h * 256;
            const int r = f >> 5;           // 0..31
            const int c = f & 31;           // 0..31
            const float4 b4 = *(const float4*)(W + (size_t)(k0 + r) * N + n0 + c * 4);
            *(float4*)&Bs[r][c * 4] = b4;
        }
        __syncthreads();

        #pragma unroll
        for (int kk = 0; kk < BK; ++kk) {
            float a[2][4], b[2][4];
            #pragma unroll
            for (int rh = 0; rh < 2; ++rh) {
                const float4 v = *(const float4*)&As[kk][rh * 64 + ty * 4];
                a[rh][0] = v.x; a[rh][1] = v.y; a[rh][2] = v.z; a[rh][3] = v.w;
            }
            #pragma unroll
            for (int ch = 0; ch < 2; ++ch) {
                const float4 v = *(const float4*)&Bs[kk][ch * 64 + tx * 4];
                b[ch][0] = v.x; b[ch][1] = v.y; b[ch][2] = v.z; b[ch][3] = v.w;
            }
            #pragma unroll
            for (int rh = 0; rh < 2; ++rh)
                #pragma unroll
                for (int i = 0; i < 4; ++i)
                    #pragma unroll
                    for (int ch = 0; ch < 2; ++ch)
                        #pragma unroll
                        for (int j = 0; j < 4; ++j)
                            acc[rh][ch][i][j] += a[rh][i] * b[ch][j];
        }
        __syncthreads();
    }

    float4 bv[2];
    #pragma unroll
    for (int ch = 0; ch < 2; ++ch)
        bv[ch] = *(const float4*)(bias + n0 + ch * 64 + tx * 4);

    #pragma unroll
    for (int rh = 0; rh < 2; ++rh) {
        #pragma unroll
        for (int i = 0; i < 4; ++i) {
            const int m = m0 + rh * 64 + ty * 4 + i;
            float* crow = C + (size_t)m * N;
            #pragma unroll
            for (int ch = 0; ch < 2; ++ch) {
                const int n = n0 + ch * 64 + tx * 4;
                float4 o;
                o.x = acc[rh][ch][i][0] + bv[ch].x;
                o.y = acc[rh][ch][i][1] + bv[ch].y;
                o.z = acc[rh][ch][i][2] + bv[ch].z;
                o.w = acc[rh][ch][i][3] + bv[ch].w;
                if (RELU) {
                    o.x = fmaxf(o.x, 0.f); o.y = fmaxf(o.y, 0.f);
                    o.z = fmaxf(o.z, 0.f); o.w = fmaxf(o.w, 0.f);
                }
                *(float4*)(crow + n) = o;
            }
        }
    }
}

// ---------------------------------------------------------------------------
// 64-tile fp32 GEMM: BM=BN=64, BK=16, 4x4 micro-tile. Optionally writes
// bf16 hi/lo split planes instead of fp32 (for dec2 -> dec3 MFMA feed).
// ---------------------------------------------------------------------------
template<bool RELU, bool SPLIT_OUT>
__global__ __launch_bounds__(256)
void gemm_kernel(const float* __restrict__ A, const float* __restrict__ W,
                 const float* __restrict__ bias, float* __restrict__ C,
                 int M, int N, int Kd,
                 unsigned short* __restrict__ Ohi, unsigned short* __restrict__ Olo)
{
    const int BM = 64, BN = 64, BK = 16;
    __shared__ float As[BK][BM + 4];
    __shared__ float Bs[BK][BN + 4];

    const int tid = threadIdx.x;
    const int tx = tid & 15;
    const int ty = tid >> 4;
    const int m0 = blockIdx.y * BM;
    const int n0 = blockIdx.x * BN;

    float acc[4][4] = {};

    for (int k0 = 0; k0 < Kd; k0 += BK) {
        {
            const int r  = tid >> 2;
            const int c4 = tid & 3;
            const float4 a4 = *(const float4*)(A + (size_t)(m0 + r) * Kd + k0 + c4 * 4);
            As[c4 * 4 + 0][r] = a4.x;
            As[c4 * 4 + 1][r] = a4.y;
            As[c4 * 4 + 2][r] = a4.z;
            As[c4 * 4 + 3][r] = a4.w;
        }
        {
            const int r  = tid >> 4;
            const int c4 = tid & 15;
            const float4 b4 = *(const float4*)(W + (size_t)(k0 + r) * N + n0 + c4 * 4);
            *(float4*)&Bs[r][c4 * 4] = b4;
        }
        __syncthreads();

        #pragma unroll
        for (int kk = 0; kk < BK; ++kk) {
            const float4 a4 = *(const float4*)&As[kk][ty * 4];
            const float4 b4 = *(const float4*)&Bs[kk][tx * 4];
            const float av[4] = {a4.x, a4.y, a4.z, a4.w};
            const float bv[4] = {b4.x, b4.y, b4.z, b4.w};
            #pragma unroll
            for (int i = 0; i < 4; ++i)
                #pragma unroll
                for (int j = 0; j < 4; ++j)
                    acc[i][j] += av[i] * bv[j];
        }
        __syncthreads();
    }

    #pragma unroll
    for (int i = 0; i < 4; ++i) {
        const int m = m0 + ty * 4 + i;
        const int n = n0 + tx * 4;
        float v[4];
        #pragma unroll
        for (int j = 0; j < 4; ++j) {
            v[j] = acc[i][j] + bias[n + j];
            if (RELU) v[j] = fmaxf(v[j], 0.f);
        }
        if (SPLIT_OUT) {
            ushort4 h4, l4;
            unsigned short* hp = (unsigned short*)&h4;
            unsigned short* lp = (unsigned short*)&l4;
            #pragma unroll
            for (int j = 0; j < 4; ++j) {
                const unsigned short hi = f2bf(v[j]);
                hp[j] = hi;
                lp[j] = f2bf(v[j] - bf2f(hi));
            }
            *(ushort4*)&Ohi[(size_t)m * N + n] = h4;
            *(ushort4*)&Olo[(size_t)m * N + n] = l4;
        } else {
            float4 o; o.x = v[0]; o.y = v[1]; o.z = v[2]; o.w = v[3];
            *(float4*)&C[(size_t)m * N + n] = o;
        }
    }
}

// ---------------------------------------------------------------------------
// Transpose + bf16-split dw3 [512][4096] fp32 -> WT hi/lo [4096][512] bf16
// ---------------------------------------------------------------------------
__global__ __launch_bounds__(256)
void split_w3t_kernel(const float* __restrict__ Win,
                      unsigned short* __restrict__ Whi,
                      unsigned short* __restrict__ Wlo)
{
    __shared__ float t[64][65];
    const int tid = threadIdx.x;
    const int tx = tid & 63;
    const int ty = tid >> 6;        // 0..3
    const int n0 = blockIdx.x * 64; // over NPTS
    const int k0 = blockIdx.y * 64; // over 512

    #pragma unroll
    for (int i = 0; i < 16; ++i) {
        const int kk = ty + i * 4;
        t[kk][tx] = Win[(size_t)(k0 + kk) * NPTS + n0 + tx];
    }
    __syncthreads();
    #pragma unroll
    for (int i = 0; i < 16; ++i) {
        const int nn = ty + i * 4;
        const float v = t[tx][nn];
        const unsigned short hi = f2bf(v);
        const size_t off = (size_t)(n0 + nn) * 512 + k0 + tx;
        Whi[off] = hi;
        Wlo[off] = f2bf(v - bf2f(hi));
    }
}

// ---------------------------------------------------------------------------
// dec3 via bf16 2-split 3-product MFMA:
//   C = (Ahi+Alo)(Whi+Wlo) ~= Ahi*Whi + Ahi*Wlo + Alo*Whi   (fp32 accum)
// A planes [M][512] bf16 (from dec2 epilogue); W planes transposed [N][512].
// BM=BN=128, BK=32, 4 waves (2x2), each wave 64x64 = 4x4 frags of 16x16.
// Fused bias + recon-loss vs X.
// ---------------------------------------------------------------------------
__global__ __launch_bounds__(256)
void mfma_dec3_kernel(const unsigned short* __restrict__ Ah,
                      const unsigned short* __restrict__ Al,
                      const unsigned short* __restrict__ Wh,
                      const unsigned short* __restrict__ Wl,
                      const float* __restrict__ bias,
                      float* __restrict__ C,
                      const float* __restrict__ X,
                      float* __restrict__ loss_acc)
{
    constexpr int K = 512, N = NPTS;
    constexpr int BM = 128, BN = 128, BK = 32;
    __shared__ __align__(16) unsigned short sAh[BM][BK];
    __shared__ __align__(16) unsigned short sAl[BM][BK];
    __shared__ __align__(16) unsigned short sBh[BN][BK];
    __shared__ __align__(16) unsigned short sBl[BN][BK];

    const int tid = threadIdx.x;
    const int w  = tid >> 6;
    const int l  = tid & 63;
    const int wr = w >> 1, wc = w & 1;   // 2x2 wave grid, 64x64 each
    const int lr = l & 15;               // frag row/col
    const int lk = l >> 4;               // k-chunk 0..3
    const int m0 = blockIdx.y * BM;
    const int n0 = blockIdx.x * BN;

    f32x4 acc[4][4];
    const f32x4 zero4 = {0.f, 0.f, 0.f, 0.f};
    #pragma unroll
    for (int i = 0; i < 4; ++i)
        #pragma unroll
        for (int j = 0; j < 4; ++j) acc[i][j] = zero4;

    // staging: 512 x 16B chunks per 8KB tile; thread handles chunks tid, tid+256
    const int r0 = tid >> 2,        kp0 = (tid & 3) * 8;
    const int r1 = (tid + 256) >> 2, kp1 = (tid & 3) * 8; // (tid+256)&3 == tid&3

    for (int k0 = 0; k0 < K; k0 += BK) {
        const uint4 vah0 = *(const uint4*)(Ah + (size_t)(m0 + r0) * K + k0 + kp0);
        const uint4 vah1 = *(const uint4*)(Ah + (size_t)(m0 + r1) * K + k0 + kp1);
        const uint4 val0 = *(const uint4*)(Al + (size_t)(m0 + r0) * K + k0 + kp0);
        const uint4 val1 = *(const uint4*)(Al + (size_t)(m0 + r1) * K + k0 + kp1);
        const uint4 vbh0 = *(const uint4*)(Wh + (size_t)(n0 + r0) * K + k0 + kp0);
        const uint4 vbh1 = *(const uint4*)(Wh + (size_t)(n0 + r1) * K + k0 + kp1);
        const uint4 vbl0 = *(const uint4*)(Wl + (size_t)(n0 + r0) * K + k0 + kp0);
        const uint4 vbl1 = *(const uint4*)(Wl + (size_t)(n0 + r1) * K + k0 + kp1);
        __syncthreads();                     // prev compute done before overwrite
        *(uint4*)&sAh[r0][kp0] = vah0;  *(uint4*)&sAh[r1][kp1] = vah1;
        *(uint4*)&sAl[r0][kp0] = val0;  *(uint4*)&sAl[r1][kp1] = val1;
        *(uint4*)&sBh[r0][kp0] = vbh0;  *(uint4*)&sBh[r1][kp1] = vbh1;
        *(uint4*)&sBl[r0][kp0] = vbl0;  *(uint4*)&sBl[r1][kp1] = vbl1;
        __syncthreads();

        bf16x8 fah[4], fal[4], fbh[4], fbl[4];
        #pragma unroll
        for (int r = 0; r < 4; ++r) {
            fah[r] = *(const bf16x8*)&sAh[wr * 64 + r * 16 + lr][lk * 8];
            fal[r] = *(const bf16x8*)&sAl[wr * 64 + r * 16 + lr][lk * 8];
        }
        #pragma unroll
        for (int c = 0; c < 4; ++c) {
            fbh[c] = *(const bf16x8*)&sBh[wc * 64 + c * 16 + lr][lk * 8];
            fbl[c] = *(const bf16x8*)&sBl[wc * 64 + c * 16 + lr][lk * 8];
        }
        #pragma unroll
        for (int r = 0; r < 4; ++r)
            #pragma unroll
            for (int c = 0; c < 4; ++c) {
                acc[r][c] = __builtin_amdgcn_mfma_f32_16x16x32_bf16(fah[r], fbh[c], acc[r][c], 0, 0, 0);
                acc[r][c] = __builtin_amdgcn_mfma_f32_16x16x32_bf16(fah[r], fbl[c], acc[r][c], 0, 0, 0);
                acc[r][c] = __builtin_amdgcn_mfma_f32_16x16x32_bf16(fal[r], fbh[c], acc[r][c], 0, 0, 0);
            }
    }

    // epilogue: C/D map (16x16x32): col = lane&15, row = (lane>>4)*4 + reg
    float lsum = 0.f;
    #pragma unroll
    for (int c = 0; c < 4; ++c) {
        const int col = n0 + wc * 64 + c * 16 + lr;
        const float bv = bias[col];
        #pragma unroll
        for (int r = 0; r < 4; ++r) {
            const int rowb = m0 + wr * 64 + r * 16 + lk * 4;
            #pragma unroll
            for (int q = 0; q < 4; ++q) {
                const float v = acc[r][c][q] + bv;
                const size_t off = (size_t)(rowb + q) * N + col;
                const float d = v - X[off];
                lsum += d * d;
                C[off] = v;
            }
        }
    }

    __shared__ float red[256];
    red[tid] = lsum;
    __syncthreads();
    for (int s = 128; s > 0; s >>= 1) {
        if (tid < s) red[tid] += red[tid + s];
        __syncthreads();
    }
    if (tid == 0) atomicAdd(loss_acc, red[0]);
}

// ---------------------------------------------------------------------------
// Codebook squared norms
// ---------------------------------------------------------------------------
__global__ __launch_bounds__(256)
void cbnorm_kernel(const float* __restrict__ cb, float* __restrict__ sc)
{
    const int c = blockIdx.x * blockDim.x + threadIdx.x;
    if (c < KCB) {
        double s = 0.0;
        #pragma unroll 16
        for (int j = 0; j < LAT; ++j) {
            const float v = cb[(size_t)c * LAT + j];
            s += (double)v * (double)v;
        }
        sc[c] = (float)s;
    }
}

// ---------------------------------------------------------------------------
// VQ assignment, 4 rows/block (unchanged from round 1)
// ---------------------------------------------------------------------------
#define VQROWS 4
__global__ __launch_bounds__(256)
void vq_assign_kernel(const float* __restrict__ z, const float* __restrict__ cb,
                      const float* __restrict__ sc, float* __restrict__ zq,
                      float* __restrict__ idx_out)
{
    __shared__ float zrow[VQROWS][LAT];
    __shared__ float sS[VQROWS];
    __shared__ float rd[256];
    __shared__ int   ri[256];

    const int row0 = blockIdx.x * VQROWS;
    const int tid = threadIdx.x;

    zrow[tid >> 6][tid & 63] = z[(size_t)row0 * LAT + tid];
    __syncthreads();
    if (tid < VQROWS) {
        double s = 0.0;
        for (int j = 0; j < LAT; ++j) s += (double)zrow[tid][j] * (double)zrow[tid][j];
        sS[tid] = (float)s;
    }
    __syncthreads();

    float bestd[VQROWS];
    int   besti[VQROWS];
    #pragma unroll
    for (int r = 0; r < VQROWS; ++r) { bestd[r] = 1e30f; besti[r] = KCB; }

    for (int c = tid; c < KCB; c += 256) {
        const float4* cb4 = (const float4*)(cb + (size_t)c * LAT);
        double dot[VQROWS] = {};
        #pragma unroll
        for (int q = 0; q < LAT / 4; ++q) {
            const float4 cv = cb4[q];
            #pragma unroll
            for (int r = 0; r < VQROWS; ++r) {
                const float4 zv = ((const float4*)zrow[r])[q];
                dot[r] += (double)zv.x * cv.x + (double)zv.y * cv.y
                        + (double)zv.z * cv.z + (double)zv.w * cv.w;
            }
        }
        #pragma unroll
        for (int r = 0; r < VQROWS; ++r) {
            const float zc = (float)dot[r];
            const float d  = (sS[r] - 2.0f * zc) + sc[c];
            if (d < bestd[r] || (d == bestd[r] && c < besti[r])) {
                bestd[r] = d; besti[r] = c;
            }
        }
    }

    for (int r = 0; r < VQROWS; ++r) {
        rd[tid] = bestd[r]; ri[tid] = besti[r];
        __syncthreads();
        for (int s = 128; s > 0; s >>= 1) {
            if (tid < s) {
                const float od = rd[tid + s];
                const int   oi = ri[tid + s];
                if (od < rd[tid] || (od == rd[tid] && oi < ri[tid])) {
                    rd[tid] = od; ri[tid] = oi;
                }
            }
            __syncthreads();
        }
        const int best = ri[0];
        if (tid == 0) idx_out[row0 + r] = (float)best;
        if (tid < LAT) zq[(size_t)(row0 + r) * LAT + tid] = cb[(size_t)best * LAT + tid];
        __syncthreads();
    }
}

// ---------------------------------------------------------------------------
__global__ __launch_bounds__(256)
void vq_loss_kernel(const float* __restrict__ z, const float* __restrict__ zq,
                    float* __restrict__ acc, int n)
{
    float s = 0.f;
    for (int i = blockIdx.x * blockDim.x + threadIdx.x; i < n;
         i += gridDim.x * blockDim.x) {
        const float d = zq[i] - z[i];
        s += d * d;
    }
    __shared__ float red[256];
    red[threadIdx.x] = s;
    __syncthreads();
    for (int t = 128; t > 0; t >>= 1) {
        if (threadIdx.x < t) red[threadIdx.x] += red[threadIdx.x + t];
        __syncthreads();
    }
    if (threadIdx.x == 0) atomicAdd(acc, red[0]);
}

// ---------------------------------------------------------------------------
__global__ void finalize_kernel(const float* __restrict__ acc, float* __restrict__ out3)
{
    const float recon = acc[0] / ((float)B_ * (float)NPTS);
    const float vq    = 1.25f * (acc[1] / ((float)B_ * (float)LAT));
    out3[0] = recon + vq;
    out3[1] = recon;
    out3[2] = vq;
}

// ---------------------------------------------------------------------------
extern "C" void kernel_launch(void* const* d_in, const int* in_sizes, int n_in,
                              void* d_out, int out_size, void* d_ws, size_t ws_size,
                              hipStream_t stream)
{
    const float* x   = (const float*)d_in[0];
    const float* ew1 = (const float*)d_in[1];
    const float* eb1 = (const float*)d_in[2];
    const float* ew2 = (const float*)d_in[3];
    const float* eb2 = (const float*)d_in[4];
    const float* ew3 = (const float*)d_in[5];
    const float* eb3 = (const float*)d_in[6];
    const float* cb  = (const float*)d_in[7];
    const float* dw1 = (const float*)d_in[8];
    const float* db1 = (const float*)d_in[9];
    const float* dw2 = (const float*)d_in[10];
    const float* db2 = (const float*)d_in[11];
    const float* dw3 = (const float*)d_in[12];
    const float* db3 = (const float*)d_in[13];

    float* out_xh     = (float*)d_out;
    float* out_idx    = out_xh + (size_t)B_ * NPTS;
    float* out_losses = out_idx + B_;

    float* ws   = (float*)d_ws;
    float* bufA = ws;                                   // h1 fp32; later h4 bf16 planes
    float* bufB = bufA + (size_t)B_ * 512;              // h2 / h3 fp32
    float* z    = bufB + (size_t)B_ * 256;
    float* zq   = z + (size_t)B_ * LAT;
    float* sc   = zq + (size_t)B_ * LAT;
    float* acc  = sc + KCB;                             // [0]=recon_sum, [1]=vq_sum
    unsigned short* wt3hi = (unsigned short*)(acc + 16);            // [NPTS][512]
    unsigned short* wt3lo = wt3hi + (size_t)NPTS * 512;
    unsigned short* h4hi  = (unsigned short*)bufA;                  // [B_][512]
    unsigned short* h4lo  = h4hi + (size_t)B_ * 512;

    hipMemsetAsync(acc, 0, 2 * sizeof(float), stream);

    const dim3 blk(256);

    // weight transpose+split (independent; cheap)
    split_w3t_kernel<<<dim3(NPTS / 64, 512 / 64), blk, 0, stream>>>(dw3, wt3hi, wt3lo);

    // encoder (arithmetic bitwise-identical to round 0/1 -> idx stable)
    gemm128_kernel<true><<<dim3(512 / 128, B_ / 128), blk, 0, stream>>>(
        x, ew1, eb1, bufA, B_, 512, NPTS);
    gemm_kernel<true, false><<<dim3(256 / 64, B_ / 64), blk, 0, stream>>>(
        bufA, ew2, eb2, bufB, B_, 256, 512, nullptr, nullptr);
    gemm_kernel<false, false><<<dim3(64 / 64, B_ / 64), blk, 0, stream>>>(
        bufB, ew3, eb3, z, B_, 64, 256, nullptr, nullptr);

    // vector quantization
    cbnorm_kernel<<<dim3(KCB / 256), blk, 0, stream>>>(cb, sc);
    vq_assign_kernel<<<dim3(B_ / VQROWS), blk, 0, stream>>>(z, cb, sc, zq, out_idx);
    vq_loss_kernel<<<dim3(256), blk, 0, stream>>>(z, zq, acc + 1, B_ * LAT);

    // decoder
    gemm_kernel<true, false><<<dim3(256 / 64, B_ / 64), blk, 0, stream>>>(
        zq, dw1, db1, bufB, B_, 256, LAT, nullptr, nullptr);
    gemm_kernel<true, true><<<dim3(512 / 64, B_ / 64), blk, 0, stream>>>(
        bufB, dw2, db2, nullptr, B_, 512, 256, h4hi, h4lo);    // h1 dead; bufA reused
    mfma_dec3_kernel<<<dim3(NPTS / 128, B_ / 128), blk, 0, stream>>>(
        h4hi, h4lo, wt3hi, wt3lo, db3, out_xh, x, acc + 0);

    finalize_kernel<<<1, 1, 0, stream>>>(acc, out_losses);
}